// Round 9
// baseline (48.060 us; speedup 1.0000x reference)
//
#include <hip/hip_runtime.h>

#define N_B 8
#define DIM 256

constexpr float C2    = 2.8853900817779268f;   // 2*log2(e)
constexpr float LOG2E = 1.4426950408889634f;

typedef __attribute__((ext_vector_type(8))) short short8;
typedef __attribute__((ext_vector_type(4))) float f32x4;
typedef unsigned short ushort_t;

__device__ __forceinline__ unsigned hi2(float a, float b) {
    return (__float_as_uint(a) >> 16) | (__float_as_uint(b) & 0xFFFF0000u);
}
__device__ __forceinline__ float trunc_res(float a) {
    return a - __uint_as_float(__float_as_uint(a) & 0xFFFF0000u);
}

// ---------------- prep: transpose + bf16 hi/lo split ----------------
__global__ __launch_bounds__(256) void prep_kernel(
    const float* __restrict__ Wq, const float* __restrict__ Wk,
    const float* __restrict__ V,
    ushort_t* __restrict__ WqT_hi, ushort_t* __restrict__ WqT_lo,
    ushort_t* __restrict__ WkT_hi, ushort_t* __restrict__ WkT_lo,
    ushort_t* __restrict__ VT_hi,  ushort_t* __restrict__ VT_lo)
{
    __shared__ __align__(16) float T[64][68];
    int id = blockIdx.x;
    const float* src; ushort_t *dhi, *dlo; int t;
    if (id < 16)      { src = Wq; dhi = WqT_hi; dlo = WqT_lo; t = id; }
    else if (id < 32) { src = Wk; dhi = WkT_hi; dlo = WkT_lo; t = id - 16; }
    else {
        int v = id - 32; int b = v >> 4; t = v & 15;
        src = V + b * DIM * DIM; dhi = VT_hi + b * DIM * DIM; dlo = VT_lo + b * DIM * DIM;
    }
    int R0 = (t >> 2) * 64, C0 = (t & 3) * 64;
    int tt = threadIdx.x;
    int r = tt >> 2, q = tt & 3;
#pragma unroll
    for (int i = 0; i < 4; ++i)
        *(float4*)&T[r][q * 16 + i * 4] = *(const float4*)&src[(size_t)(R0 + r) * DIM + C0 + q * 16 + i * 4];
    __syncthreads();
    float f[16];
#pragma unroll
    for (int j = 0; j < 16; ++j) f[j] = T[q * 16 + j][r];
    unsigned h[8], l[8];
#pragma unroll
    for (int j = 0; j < 8; ++j) {
        h[j] = hi2(f[2 * j], f[2 * j + 1]);
        l[j] = hi2(trunc_res(f[2 * j]), trunc_res(f[2 * j + 1]));
    }
    size_t base = (size_t)(C0 + r) * DIM + R0 + q * 16;
    *(uint4*)&dhi[base]     = make_uint4(h[0], h[1], h[2], h[3]);
    *(uint4*)&dhi[base + 8] = make_uint4(h[4], h[5], h[6], h[7]);
    *(uint4*)&dlo[base]     = make_uint4(l[0], l[1], l[2], l[3]);
    *(uint4*)&dlo[base + 8] = make_uint4(l[4], l[5], l[6], l[7]);
}

// ---------------- proj (MFMA): EQ[b][h][n]=exp2(C2*(A@W)) transposed, EK[b][m][h] ----------------
__global__ __launch_bounds__(256) void proj_mfma(
    const float* __restrict__ query, const float* __restrict__ key,
    const ushort_t* __restrict__ WqT_hi, const ushort_t* __restrict__ WqT_lo,
    const ushort_t* __restrict__ WkT_hi, const ushort_t* __restrict__ WkT_lo,
    float* __restrict__ EQ, float* __restrict__ EK)
{
    __shared__ __align__(16) ushort_t Ah[64 * 64], Al[64 * 64], Bh[64 * 64], Bl[64 * 64];
    __shared__ __align__(16) float T[64][68];

    int y = blockIdx.y;
    int b = y >> 1; bool isK = y & 1;
    const float* A = (isK ? key : query) + b * DIM * DIM;
    const ushort_t* BThi = isK ? WkT_hi : WqT_hi;
    const ushort_t* BTlo = isK ? WkT_lo : WqT_lo;

    int x = blockIdx.x;
    int R0 = (x >> 2) * 64, C0 = (x & 3) * 64;

    int tid = threadIdx.x;
    int w = tid >> 6, lane = tid & 63;
    int wr = w >> 1, wc = w & 1;
    int l15 = lane & 15, l4 = lane >> 4;

    int sr = tid >> 2, skq = (tid & 3) * 16;

    f32x4 acc[2][2] = {};
    float4 areg0, areg1, areg2, areg3;
    uint4 bh0, bh1, bl0, bl1;

    {
        const float* ap = &A[(size_t)(R0 + sr) * DIM + skq];
        areg0 = *(const float4*)&ap[0];  areg1 = *(const float4*)&ap[4];
        areg2 = *(const float4*)&ap[8];  areg3 = *(const float4*)&ap[12];
        size_t bb = (size_t)(C0 + sr) * DIM + skq;
        bh0 = *(const uint4*)&BThi[bb]; bh1 = *(const uint4*)&BThi[bb + 8];
        bl0 = *(const uint4*)&BTlo[bb]; bl1 = *(const uint4*)&BTlo[bb + 8];
    }

    for (int ks = 0; ks < 4; ++ks) {
        {
            int i0 = (sr * 64 + skq)     ^ ((sr & 7) << 3);
            int i1 = (sr * 64 + skq + 8) ^ ((sr & 7) << 3);
            uint4 hv0 = make_uint4(hi2(areg0.x, areg0.y), hi2(areg0.z, areg0.w),
                                   hi2(areg1.x, areg1.y), hi2(areg1.z, areg1.w));
            uint4 hv1 = make_uint4(hi2(areg2.x, areg2.y), hi2(areg2.z, areg2.w),
                                   hi2(areg3.x, areg3.y), hi2(areg3.z, areg3.w));
            uint4 lv0 = make_uint4(hi2(trunc_res(areg0.x), trunc_res(areg0.y)),
                                   hi2(trunc_res(areg0.z), trunc_res(areg0.w)),
                                   hi2(trunc_res(areg1.x), trunc_res(areg1.y)),
                                   hi2(trunc_res(areg1.z), trunc_res(areg1.w)));
            uint4 lv1 = make_uint4(hi2(trunc_res(areg2.x), trunc_res(areg2.y)),
                                   hi2(trunc_res(areg2.z), trunc_res(areg2.w)),
                                   hi2(trunc_res(areg3.x), trunc_res(areg3.y)),
                                   hi2(trunc_res(areg3.z), trunc_res(areg3.w)));
            *(uint4*)&Ah[i0] = hv0; *(uint4*)&Ah[i1] = hv1;
            *(uint4*)&Al[i0] = lv0; *(uint4*)&Al[i1] = lv1;
            *(uint4*)&Bh[i0] = bh0; *(uint4*)&Bh[i1] = bh1;
            *(uint4*)&Bl[i0] = bl0; *(uint4*)&Bl[i1] = bl1;
        }
        __syncthreads();
        if (ks < 3) {
            int K0 = (ks + 1) * 64;
            const float* ap = &A[(size_t)(R0 + sr) * DIM + K0 + skq];
            areg0 = *(const float4*)&ap[0];  areg1 = *(const float4*)&ap[4];
            areg2 = *(const float4*)&ap[8];  areg3 = *(const float4*)&ap[12];
            size_t bb = (size_t)(C0 + sr) * DIM + K0 + skq;
            bh0 = *(const uint4*)&BThi[bb]; bh1 = *(const uint4*)&BThi[bb + 8];
            bl0 = *(const uint4*)&BTlo[bb]; bl1 = *(const uint4*)&BTlo[bb + 8];
        }
#pragma unroll
        for (int kk = 0; kk < 2; ++kk) {
            int kb = kk * 32 + l4 * 8;
            short8 ah[2], al[2], bh[2], bl[2];
#pragma unroll
            for (int h = 0; h < 2; ++h) {
                int arow = wr * 32 + h * 16 + l15;
                int aidx = (arow * 64 + kb) ^ ((arow & 7) << 3);
                ah[h] = *(const short8*)&Ah[aidx];
                al[h] = *(const short8*)&Al[aidx];
                int bcol = wc * 32 + h * 16 + l15;
                int bidx = (bcol * 64 + kb) ^ ((bcol & 7) << 3);
                bh[h] = *(const short8*)&Bh[bidx];
                bl[h] = *(const short8*)&Bl[bidx];
            }
#pragma unroll
            for (int i = 0; i < 2; ++i)
#pragma unroll
                for (int j = 0; j < 2; ++j) {
                    acc[i][j] = __builtin_amdgcn_mfma_f32_16x16x32_bf16(ah[i], bh[j], acc[i][j], 0, 0, 0);
                    acc[i][j] = __builtin_amdgcn_mfma_f32_16x16x32_bf16(ah[i], bl[j], acc[i][j], 0, 0, 0);
                    acc[i][j] = __builtin_amdgcn_mfma_f32_16x16x32_bf16(al[i], bh[j], acc[i][j], 0, 0, 0);
                }
        }
        __syncthreads();
    }

#pragma unroll
    for (int i = 0; i < 2; ++i)
#pragma unroll
        for (int j = 0; j < 2; ++j) {
            float ev[4];
#pragma unroll
            for (int v = 0; v < 4; ++v) ev[v] = __builtin_amdgcn_exp2f(C2 * acc[i][j][v]);
            int row = wr * 32 + i * 16 + l4 * 4;
            int col = wc * 32 + j * 16 + l15;
            if (isK) {
#pragma unroll
                for (int v = 0; v < 4; ++v) T[row + v][col] = ev[v];
            } else {
                *(float4*)&T[col][row] = make_float4(ev[0], ev[1], ev[2], ev[3]);
            }
        }
    __syncthreads();
    {
        int r = tid >> 2, q = tid & 3;
        float* dst = isK ? &EK[(size_t)b * DIM * DIM + (size_t)(R0 + r) * DIM + C0 + q * 16]
                         : &EQ[(size_t)b * DIM * DIM + (size_t)(C0 + r) * DIM + R0 + q * 16];
#pragma unroll
        for (int i = 0; i < 4; ++i)
            *(float4*)&dst[i * 4] = *(const float4*)&T[r][q * 16 + i * 4];
    }
}

// ---------------- fused scores + softmax(axis=n) -> attnN hi/lo bf16 [n][m] ----------------
// Uniform operands (Wv, EK rows) now loaded from GLOBAL with readfirstlane offsets
// (scalarizable; off the LDS pipe), software-pipelined one chunk ahead.
#define CH 16
__global__ __launch_bounds__(512, 2) void scores_softmax_kernel(
    const float* __restrict__ EQ, const float* __restrict__ EK,
    const float* __restrict__ Wv,
    ushort_t* __restrict__ ANh, ushort_t* __restrict__ ANl)
{
    int b  = blockIdx.y;
    int M0 = blockIdx.x * 8;
    const float* Qb = EQ + b * DIM * DIM;   // [h][n]
    const float* Kb = EK + b * DIM * DIM;   // [m][h]

    __shared__ __align__(16) float Qs[2][CH * 256];    // 32 KB dbuf h-chunks
    __shared__ __align__(16) float part[3][2][64][16]; // 24 KB h-split exchange

    int tid  = threadIdx.x;
    int w = tid >> 6, lane = tid & 63;
    int mg = w & 1, hs = w >> 1;      // m-group 0..1, h-split 0..3
    int n0 = lane * 4;

    // chunk 0 staging
    *(float4*)&Qs[0][tid * 4]        = *(const float4*)&Qb[tid * 4];
    *(float4*)&Qs[0][2048 + tid * 4] = *(const float4*)&Qb[2048 + tid * 4];

    // wsum from global (coalesced) + wave reduce
    float wsum = Wv[lane] + Wv[lane + 64] + Wv[lane + 128] + Wv[lane + 192];
#pragma unroll
    for (int o = 32; o; o >>= 1) wsum += __shfl_xor(wsum, o);

    int kbase = (M0 + mg * 4) * DIM;  // wave-uniform EK row base

    // preload uniforms for chunk 0 (scalar offsets)
    float4 wv_c, e0_c, e1_c, e2_c, e3_c;
    {
        int offW = __builtin_amdgcn_readfirstlane(hs * 4);
        int offK = __builtin_amdgcn_readfirstlane(kbase + hs * 4);
        wv_c = *(const float4*)&Wv[offW];
        e0_c = *(const float4*)&Kb[offK];
        e1_c = *(const float4*)&Kb[offK + 256];
        e2_c = *(const float4*)&Kb[offK + 512];
        e3_c = *(const float4*)&Kb[offK + 768];
    }
    __syncthreads();

    float acc[4][4] = {};   // [m-row][n]
    int buf = 0;

    for (int c = 0; c < 16; ++c) {
        float4 nx0, nx1, wv_n, e0_n, e1_n, e2_n, e3_n;
        if (c < 15) {
            const float* s = Qb + (c + 1) * (CH * 256);
            nx0 = *(const float4*)&s[tid * 4];
            nx1 = *(const float4*)&s[2048 + tid * 4];
            int offW = __builtin_amdgcn_readfirstlane((c + 1) * CH + hs * 4);
            int offK = __builtin_amdgcn_readfirstlane(kbase + (c + 1) * CH + hs * 4);
            wv_n = *(const float4*)&Wv[offW];
            e0_n = *(const float4*)&Kb[offK];
            e1_n = *(const float4*)&Kb[offK + 256];
            e2_n = *(const float4*)&Kb[offK + 512];
            e3_n = *(const float4*)&Kb[offK + 768];
        }
        float wva[4] = {wv_c.x, wv_c.y, wv_c.z, wv_c.w};
        float eka[4][4] = {{e0_c.x, e0_c.y, e0_c.z, e0_c.w},
                           {e1_c.x, e1_c.y, e1_c.z, e1_c.w},
                           {e2_c.x, e2_c.y, e2_c.z, e2_c.w},
                           {e3_c.x, e3_c.y, e3_c.z, e3_c.w}};
        const float* Qc = &Qs[buf][(hs * 4) * 256];
#pragma unroll
        for (int hh = 0; hh < 2; ++hh) {
            float4 q0 = *(const float4*)&Qc[(hh * 2) * 256 + n0];
            float4 q1 = *(const float4*)&Qc[(hh * 2 + 1) * 256 + n0];
            float q0a[4] = {q0.x, q0.y, q0.z, q0.w};
            float q1a[4] = {q1.x, q1.y, q1.z, q1.w};
            float w0 = wva[hh * 2], w1 = wva[hh * 2 + 1];
#pragma unroll
            for (int i = 0; i < 4; ++i) {
                float e0 = eka[i][hh * 2], e1 = eka[i][hh * 2 + 1];
#pragma unroll
                for (int j = 0; j < 4; ++j) {
                    float d0 = fmaf(q0a[j], e0, 1.0f);
                    float d1 = fmaf(q1a[j], e1, 1.0f);
                    float num = fmaf(w0, d1, w1 * d0);
                    acc[i][j] = fmaf(num, __builtin_amdgcn_rcpf(d0 * d1), acc[i][j]);
                }
            }
        }
        if (c < 15) {
            *(float4*)&Qs[buf ^ 1][tid * 4] = nx0;
            *(float4*)&Qs[buf ^ 1][2048 + tid * 4] = nx1;
            wv_c = wv_n; e0_c = e0_n; e1_c = e1_n; e2_c = e2_n; e3_c = e3_n;
        }
        __syncthreads();
        buf ^= 1;
    }

    if (hs) {
#pragma unroll
        for (int i = 0; i < 4; ++i) {
            float4 v = make_float4(acc[i][0], acc[i][1], acc[i][2], acc[i][3]);
            *(float4*)&part[hs - 1][mg][lane][i * 4] = v;
        }
    }
    __syncthreads();
    if (hs == 0) {
#pragma unroll
        for (int p = 0; p < 3; ++p)
#pragma unroll
            for (int i = 0; i < 4; ++i) {
                float4 v = *(const float4*)&part[p][mg][lane][i * 4];
                acc[i][0] += v.x; acc[i][1] += v.y; acc[i][2] += v.z; acc[i][3] += v.w;
            }
        float e[4][4], t[4], ri[4];
#pragma unroll
        for (int i = 0; i < 4; ++i) {
            t[i] = 0.0f;
#pragma unroll
            for (int j = 0; j < 4; ++j) {
                e[i][j] = __builtin_amdgcn_exp2f((wsum - 2.0f * acc[i][j]) * LOG2E);
                t[i] += e[i][j];
            }
        }
#pragma unroll
        for (int o = 32; o; o >>= 1)
#pragma unroll
            for (int i = 0; i < 4; ++i) t[i] += __shfl_xor(t[i], o);
#pragma unroll
        for (int i = 0; i < 4; ++i) ri[i] = __builtin_amdgcn_rcpf(t[i]);
#pragma unroll
        for (int j = 0; j < 4; ++j) {
            float a0 = e[0][j] * ri[0], a1 = e[1][j] * ri[1];
            float a2 = e[2][j] * ri[2], a3 = e[3][j] * ri[3];
            size_t base = ((size_t)b * DIM + n0 + j) * DIM + M0 + mg * 4;
            *(uint2*)&ANh[base] = make_uint2(hi2(a0, a1), hi2(a2, a3));
            *(uint2*)&ANl[base] = make_uint2(hi2(trunc_res(a0), trunc_res(a1)),
                                             hi2(trunc_res(a2), trunc_res(a3)));
        }
    }
}

// ---------------- av (MFMA): out[b][n][d] = sum_m attnN[n][m] * V[m][d] ----------------
__global__ __launch_bounds__(256) void av_mfma(
    const ushort_t* __restrict__ ANh, const ushort_t* __restrict__ ANl,
    const ushort_t* __restrict__ VTh, const ushort_t* __restrict__ VTl,
    float* __restrict__ out)
{
    __shared__ __align__(16) ushort_t Ah[64 * 64], Al[64 * 64], Bh[64 * 64], Bl[64 * 64];
    __shared__ __align__(16) float T[64][68];

    int b = blockIdx.y;
    int x = blockIdx.x;
    int R0 = (x >> 2) * 64, C0 = (x & 3) * 64;
    const ushort_t* Abh = ANh + (size_t)b * DIM * DIM;
    const ushort_t* Abl = ANl + (size_t)b * DIM * DIM;
    const ushort_t* Bbh = VTh + (size_t)b * DIM * DIM;
    const ushort_t* Bbl = VTl + (size_t)b * DIM * DIM;

    int tid = threadIdx.x;
    int w = tid >> 6, lane = tid & 63;
    int wr = w >> 1, wc = w & 1;
    int l15 = lane & 15, l4 = lane >> 4;
    int sr = tid >> 2, skq = (tid & 3) * 16;

    f32x4 acc[2][2] = {};
    uint4 ah0, ah1, al0, al1, bh0, bh1, bl0, bl1;
    {
        size_t aa = (size_t)(R0 + sr) * DIM + skq;
        size_t bb = (size_t)(C0 + sr) * DIM + skq;
        ah0 = *(const uint4*)&Abh[aa]; ah1 = *(const uint4*)&Abh[aa + 8];
        al0 = *(const uint4*)&Abl[aa]; al1 = *(const uint4*)&Abl[aa + 8];
        bh0 = *(const uint4*)&Bbh[bb]; bh1 = *(const uint4*)&Bbh[bb + 8];
        bl0 = *(const uint4*)&Bbl[bb]; bl1 = *(const uint4*)&Bbl[bb + 8];
    }

    for (int ks = 0; ks < 4; ++ks) {
        {
            int i0 = (sr * 64 + skq)     ^ ((sr & 7) << 3);
            int i1 = (sr * 64 + skq + 8) ^ ((sr & 7) << 3);
            *(uint4*)&Ah[i0] = ah0; *(uint4*)&Ah[i1] = ah1;
            *(uint4*)&Al[i0] = al0; *(uint4*)&Al[i1] = al1;
            *(uint4*)&Bh[i0] = bh0; *(uint4*)&Bh[i1] = bh1;
            *(uint4*)&Bl[i0] = bl0; *(uint4*)&Bl[i1] = bl1;
        }
        __syncthreads();
        if (ks < 3) {
            int K0 = (ks + 1) * 64;
            size_t aa = (size_t)(R0 + sr) * DIM + K0 + skq;
            size_t bb = (size_t)(C0 + sr) * DIM + K0 + skq;
            ah0 = *(const uint4*)&Abh[aa]; ah1 = *(const uint4*)&Abh[aa + 8];
            al0 = *(const uint4*)&Abl[aa]; al1 = *(const uint4*)&Abl[aa + 8];
            bh0 = *(const uint4*)&Bbh[bb]; bh1 = *(const uint4*)&Bbh[bb + 8];
            bl0 = *(const uint4*)&Bbl[bb]; bl1 = *(const uint4*)&Bbl[bb + 8];
        }
#pragma unroll
        for (int kk = 0; kk < 2; ++kk) {
            int kb = kk * 32 + l4 * 8;
            short8 ah[2], al[2], bh[2], bl[2];
#pragma unroll
            for (int h = 0; h < 2; ++h) {
                int arow = wr * 32 + h * 16 + l15;
                int aidx = (arow * 64 + kb) ^ ((arow & 7) << 3);
                ah[h] = *(const short8*)&Ah[aidx];
                al[h] = *(const short8*)&Al[aidx];
                int bcol = wc * 32 + h * 16 + l15;
                int bidx = (bcol * 64 + kb) ^ ((bcol & 7) << 3);
                bh[h] = *(const short8*)&Bh[bidx];
                bl[h] = *(const short8*)&Bl[bidx];
            }
#pragma unroll
            for (int i = 0; i < 2; ++i)
#pragma unroll
                for (int j = 0; j < 2; ++j) {
                    acc[i][j] = __builtin_amdgcn_mfma_f32_16x16x32_bf16(ah[i], bh[j], acc[i][j], 0, 0, 0);
                    acc[i][j] = __builtin_amdgcn_mfma_f32_16x16x32_bf16(ah[i], bl[j], acc[i][j], 0, 0, 0);
                    acc[i][j] = __builtin_amdgcn_mfma_f32_16x16x32_bf16(al[i], bh[j], acc[i][j], 0, 0, 0);
                }
        }
        __syncthreads();
    }

#pragma unroll
    for (int i = 0; i < 2; ++i)
#pragma unroll
        for (int j = 0; j < 2; ++j) {
            int row = wr * 32 + i * 16 + l4 * 4;
            int col = wc * 32 + j * 16 + l15;
#pragma unroll
            for (int v = 0; v < 4; ++v) T[row + v][col] = acc[i][j][v];
        }
    __syncthreads();
    {
        int r = tid >> 2, q = tid & 3;
        float* dst = &out[((size_t)b * DIM + R0 + r) * DIM + C0 + q * 16];
#pragma unroll
        for (int i = 0; i < 4; ++i)
            *(float4*)&dst[i * 4] = *(const float4*)&T[r][q * 16 + i * 4];
    }
}

extern "C" void kernel_launch(void* const* d_in, const int* in_sizes, int n_in,
                              void* d_out, int out_size, void* d_ws, size_t ws_size,
                              hipStream_t stream)
{
    const float* query = (const float*)d_in[0];
    const float* key   = (const float*)d_in[1];
    const float* value = (const float*)d_in[2];
    const float* Wq    = (const float*)d_in[3];
    const float* Wk    = (const float*)d_in[4];
    const float* Wv    = (const float*)d_in[5];
    float* out = (float*)d_out;

    float* EQ = (float*)d_ws;                     // [8][h][n] fp32
    float* EK = EQ + N_B * DIM * DIM;             // [8][m][h] fp32
    ushort_t* us = (ushort_t*)(EK + N_B * DIM * DIM);
    ushort_t* WqT_hi = us; us += DIM * DIM;
    ushort_t* WqT_lo = us; us += DIM * DIM;
    ushort_t* WkT_hi = us; us += DIM * DIM;
    ushort_t* WkT_lo = us; us += DIM * DIM;
    ushort_t* VT_hi  = us; us += N_B * DIM * DIM;
    ushort_t* VT_lo  = us; us += N_B * DIM * DIM;
    ushort_t* ANh    = us; us += N_B * DIM * DIM;
    ushort_t* ANl    = us; us += N_B * DIM * DIM;

    prep_kernel<<<160, 256, 0, stream>>>(Wq, Wk, value,
                                         WqT_hi, WqT_lo, WkT_hi, WkT_lo, VT_hi, VT_lo);
    proj_mfma<<<dim3(16, 16), 256, 0, stream>>>(query, key,
                                                WqT_hi, WqT_lo, WkT_hi, WkT_lo, EQ, EK);
    scores_softmax_kernel<<<dim3(32, 8), 512, 0, stream>>>(EQ, EK, Wv, ANh, ANl);
    av_mfma<<<dim3(16, 8), 256, 0, stream>>>(ANh, ANl, VT_hi, VT_lo, out);
}

// Round 11
// 46.388 us; speedup vs baseline: 1.0360x; 1.0360x over previous
//
#include <hip/hip_runtime.h>

#define N_B 8
#define DIM 256

constexpr float C2    = 2.8853900817779268f;   // 2*log2(e)
constexpr float LOG2E = 1.4426950408889634f;

typedef __attribute__((ext_vector_type(8))) short short8;
typedef __attribute__((ext_vector_type(4))) float f32x4;
typedef unsigned short ushort_t;

__device__ __forceinline__ unsigned hi2(float a, float b) {
    return (__float_as_uint(a) >> 16) | (__float_as_uint(b) & 0xFFFF0000u);
}
__device__ __forceinline__ float trunc_res(float a) {
    return a - __uint_as_float(__float_as_uint(a) & 0xFFFF0000u);
}

// ---------------- prep: transpose + bf16 hi/lo split ----------------
__global__ __launch_bounds__(256) void prep_kernel(
    const float* __restrict__ Wq, const float* __restrict__ Wk,
    const float* __restrict__ V,
    ushort_t* __restrict__ WqT_hi, ushort_t* __restrict__ WqT_lo,
    ushort_t* __restrict__ WkT_hi, ushort_t* __restrict__ WkT_lo,
    ushort_t* __restrict__ VT_hi,  ushort_t* __restrict__ VT_lo)
{
    __shared__ __align__(16) float T[64][68];
    int id = blockIdx.x;
    const float* src; ushort_t *dhi, *dlo; int t;
    if (id < 16)      { src = Wq; dhi = WqT_hi; dlo = WqT_lo; t = id; }
    else if (id < 32) { src = Wk; dhi = WkT_hi; dlo = WkT_lo; t = id - 16; }
    else {
        int v = id - 32; int b = v >> 4; t = v & 15;
        src = V + b * DIM * DIM; dhi = VT_hi + b * DIM * DIM; dlo = VT_lo + b * DIM * DIM;
    }
    int R0 = (t >> 2) * 64, C0 = (t & 3) * 64;
    int tt = threadIdx.x;
    int r = tt >> 2, q = tt & 3;
#pragma unroll
    for (int i = 0; i < 4; ++i)
        *(float4*)&T[r][q * 16 + i * 4] = *(const float4*)&src[(size_t)(R0 + r) * DIM + C0 + q * 16 + i * 4];
    __syncthreads();
    float f[16];
#pragma unroll
    for (int j = 0; j < 16; ++j) f[j] = T[q * 16 + j][r];
    unsigned h[8], l[8];
#pragma unroll
    for (int j = 0; j < 8; ++j) {
        h[j] = hi2(f[2 * j], f[2 * j + 1]);
        l[j] = hi2(trunc_res(f[2 * j]), trunc_res(f[2 * j + 1]));
    }
    size_t base = (size_t)(C0 + r) * DIM + R0 + q * 16;
    *(uint4*)&dhi[base]     = make_uint4(h[0], h[1], h[2], h[3]);
    *(uint4*)&dhi[base + 8] = make_uint4(h[4], h[5], h[6], h[7]);
    *(uint4*)&dlo[base]     = make_uint4(l[0], l[1], l[2], l[3]);
    *(uint4*)&dlo[base + 8] = make_uint4(l[4], l[5], l[6], l[7]);
}

// ---------------- proj (MFMA): EQ[b][h][n]=exp2(C2*(A@W)) transposed, EK[b][m][h] ----------------
__global__ __launch_bounds__(256) void proj_mfma(
    const float* __restrict__ query, const float* __restrict__ key,
    const ushort_t* __restrict__ WqT_hi, const ushort_t* __restrict__ WqT_lo,
    const ushort_t* __restrict__ WkT_hi, const ushort_t* __restrict__ WkT_lo,
    float* __restrict__ EQ, float* __restrict__ EK)
{
    __shared__ __align__(16) ushort_t Ah[64 * 64], Al[64 * 64], Bh[64 * 64], Bl[64 * 64];
    __shared__ __align__(16) float T[64][68];

    int y = blockIdx.y;
    int b = y >> 1; bool isK = y & 1;
    const float* A = (isK ? key : query) + b * DIM * DIM;
    const ushort_t* BThi = isK ? WkT_hi : WqT_hi;
    const ushort_t* BTlo = isK ? WkT_lo : WqT_lo;

    int x = blockIdx.x;
    int R0 = (x >> 2) * 64, C0 = (x & 3) * 64;

    int tid = threadIdx.x;
    int w = tid >> 6, lane = tid & 63;
    int wr = w >> 1, wc = w & 1;
    int l15 = lane & 15, l4 = lane >> 4;

    int sr = tid >> 2, skq = (tid & 3) * 16;

    f32x4 acc[2][2] = {};
    float4 areg0, areg1, areg2, areg3;
    uint4 bh0, bh1, bl0, bl1;

    {
        const float* ap = &A[(size_t)(R0 + sr) * DIM + skq];
        areg0 = *(const float4*)&ap[0];  areg1 = *(const float4*)&ap[4];
        areg2 = *(const float4*)&ap[8];  areg3 = *(const float4*)&ap[12];
        size_t bb = (size_t)(C0 + sr) * DIM + skq;
        bh0 = *(const uint4*)&BThi[bb]; bh1 = *(const uint4*)&BThi[bb + 8];
        bl0 = *(const uint4*)&BTlo[bb]; bl1 = *(const uint4*)&BTlo[bb + 8];
    }

    for (int ks = 0; ks < 4; ++ks) {
        {
            int i0 = (sr * 64 + skq)     ^ ((sr & 7) << 3);
            int i1 = (sr * 64 + skq + 8) ^ ((sr & 7) << 3);
            uint4 hv0 = make_uint4(hi2(areg0.x, areg0.y), hi2(areg0.z, areg0.w),
                                   hi2(areg1.x, areg1.y), hi2(areg1.z, areg1.w));
            uint4 hv1 = make_uint4(hi2(areg2.x, areg2.y), hi2(areg2.z, areg2.w),
                                   hi2(areg3.x, areg3.y), hi2(areg3.z, areg3.w));
            uint4 lv0 = make_uint4(hi2(trunc_res(areg0.x), trunc_res(areg0.y)),
                                   hi2(trunc_res(areg0.z), trunc_res(areg0.w)),
                                   hi2(trunc_res(areg1.x), trunc_res(areg1.y)),
                                   hi2(trunc_res(areg1.z), trunc_res(areg1.w)));
            uint4 lv1 = make_uint4(hi2(trunc_res(areg2.x), trunc_res(areg2.y)),
                                   hi2(trunc_res(areg2.z), trunc_res(areg2.w)),
                                   hi2(trunc_res(areg3.x), trunc_res(areg3.y)),
                                   hi2(trunc_res(areg3.z), trunc_res(areg3.w)));
            *(uint4*)&Ah[i0] = hv0; *(uint4*)&Ah[i1] = hv1;
            *(uint4*)&Al[i0] = lv0; *(uint4*)&Al[i1] = lv1;
            *(uint4*)&Bh[i0] = bh0; *(uint4*)&Bh[i1] = bh1;
            *(uint4*)&Bl[i0] = bl0; *(uint4*)&Bl[i1] = bl1;
        }
        __syncthreads();
        if (ks < 3) {
            int K0 = (ks + 1) * 64;
            const float* ap = &A[(size_t)(R0 + sr) * DIM + K0 + skq];
            areg0 = *(const float4*)&ap[0];  areg1 = *(const float4*)&ap[4];
            areg2 = *(const float4*)&ap[8];  areg3 = *(const float4*)&ap[12];
            size_t bb = (size_t)(C0 + sr) * DIM + K0 + skq;
            bh0 = *(const uint4*)&BThi[bb]; bh1 = *(const uint4*)&BThi[bb + 8];
            bl0 = *(const uint4*)&BTlo[bb]; bl1 = *(const uint4*)&BTlo[bb + 8];
        }
#pragma unroll
        for (int kk = 0; kk < 2; ++kk) {
            int kb = kk * 32 + l4 * 8;
            short8 ah[2], al[2], bh[2], bl[2];
#pragma unroll
            for (int h = 0; h < 2; ++h) {
                int arow = wr * 32 + h * 16 + l15;
                int aidx = (arow * 64 + kb) ^ ((arow & 7) << 3);
                ah[h] = *(const short8*)&Ah[aidx];
                al[h] = *(const short8*)&Al[aidx];
                int bcol = wc * 32 + h * 16 + l15;
                int bidx = (bcol * 64 + kb) ^ ((bcol & 7) << 3);
                bh[h] = *(const short8*)&Bh[bidx];
                bl[h] = *(const short8*)&Bl[bidx];
            }
#pragma unroll
            for (int i = 0; i < 2; ++i)
#pragma unroll
                for (int j = 0; j < 2; ++j) {
                    acc[i][j] = __builtin_amdgcn_mfma_f32_16x16x32_bf16(ah[i], bh[j], acc[i][j], 0, 0, 0);
                    acc[i][j] = __builtin_amdgcn_mfma_f32_16x16x32_bf16(ah[i], bl[j], acc[i][j], 0, 0, 0);
                    acc[i][j] = __builtin_amdgcn_mfma_f32_16x16x32_bf16(al[i], bh[j], acc[i][j], 0, 0, 0);
                }
        }
        __syncthreads();
    }

#pragma unroll
    for (int i = 0; i < 2; ++i)
#pragma unroll
        for (int j = 0; j < 2; ++j) {
            float ev[4];
#pragma unroll
            for (int v = 0; v < 4; ++v) ev[v] = __builtin_amdgcn_exp2f(C2 * acc[i][j][v]);
            int row = wr * 32 + i * 16 + l4 * 4;
            int col = wc * 32 + j * 16 + l15;
            if (isK) {
#pragma unroll
                for (int v = 0; v < 4; ++v) T[row + v][col] = ev[v];
            } else {
                *(float4*)&T[col][row] = make_float4(ev[0], ev[1], ev[2], ev[3]);
            }
        }
    __syncthreads();
    {
        int r = tid >> 2, q = tid & 3;
        float* dst = isK ? &EK[(size_t)b * DIM * DIM + (size_t)(R0 + r) * DIM + C0 + q * 16]
                         : &EQ[(size_t)b * DIM * DIM + (size_t)(C0 + r) * DIM + R0 + q * 16];
#pragma unroll
        for (int i = 0; i < 4; ++i)
            *(float4*)&dst[i * 4] = *(const float4*)&T[r][q * 16 + i * 4];
    }
}

// ---------------- fused scores + softmax(axis=n) -> attnN hi/lo bf16 [n][m] ----------------
// Barrier-free main loop: Q read directly from global (L2-resident), ek/wv from
// small LDS broadcasts staged once. Block = 256 thr = 4 waves = 4 h-splits;
// M_B = 4 m-rows; lane = 4m x 4n. Grid 512 blocks (2/CU).
__global__ __launch_bounds__(256, 2) void scores_softmax_kernel(
    const float* __restrict__ EQ, const float* __restrict__ EK,
    const float* __restrict__ Wv,
    ushort_t* __restrict__ ANh, ushort_t* __restrict__ ANl)
{
    int b  = blockIdx.y;
    int M0 = blockIdx.x * 4;
    const float* Qb = EQ + b * DIM * DIM;   // [h][n]
    const float* Kb = EK + b * DIM * DIM;   // [m][h]

    __shared__ __align__(16) float Eks[4][DIM];     // 4 KB
    __shared__ __align__(16) float Ws[DIM];         // 1 KB
    __shared__ __align__(16) float part[3][64][16]; // 12 KB h-split exchange

    int tid  = threadIdx.x;
    int hs = tid >> 6, lane = tid & 63;   // wave = h-split 0..3
    int n0 = lane * 4;

    {   // stage Eks (4 m-rows) + Ws once
        int row = tid >> 6, h4 = (tid & 63) * 4;
        *(float4*)&Eks[row][h4] = *(const float4*)&Kb[(M0 + row) * DIM + h4];
    }
    if (tid < 64) *(float4*)&Ws[tid * 4] = *(const float4*)&Wv[tid * 4];

    float wsum = Wv[lane] + Wv[lane + 64] + Wv[lane + 128] + Wv[lane + 192];
#pragma unroll
    for (int o = 32; o; o >>= 1) wsum += __shfl_xor(wsum, o);
    __syncthreads();

    float acc[4][4] = {};   // [m-row][n]
    const float* qbase = Qb + (hs * 4) * 256 + n0;   // this wave's h-offset

#pragma unroll 2
    for (int c = 0; c < 16; ++c) {
        // wave-uniform chunk values (LDS broadcasts)
        float4 wv4 = *(const float4*)&Ws[c * 16 + hs * 4];
        float wva[4] = {wv4.x, wv4.y, wv4.z, wv4.w};
        float eka[4][4];
#pragma unroll
        for (int i = 0; i < 4; ++i) {
            float4 e4 = *(const float4*)&Eks[i][c * 16 + hs * 4];
            eka[i][0] = e4.x; eka[i][1] = e4.y; eka[i][2] = e4.z; eka[i][3] = e4.w;
        }
        const float* qc = qbase + c * 16 * 256;
#pragma unroll
        for (int hh = 0; hh < 2; ++hh) {
            float4 q0 = *(const float4*)&qc[(hh * 2) * 256];
            float4 q1 = *(const float4*)&qc[(hh * 2 + 1) * 256];
            float q0a[4] = {q0.x, q0.y, q0.z, q0.w};
            float q1a[4] = {q1.x, q1.y, q1.z, q1.w};
            float w0 = wva[hh * 2], w1 = wva[hh * 2 + 1];
#pragma unroll
            for (int i = 0; i < 4; ++i) {
                float e0 = eka[i][hh * 2], e1 = eka[i][hh * 2 + 1];
#pragma unroll
                for (int j = 0; j < 4; ++j) {
                    float d0 = fmaf(q0a[j], e0, 1.0f);
                    float d1 = fmaf(q1a[j], e1, 1.0f);
                    float num = fmaf(w0, d1, w1 * d0);
                    acc[i][j] = fmaf(num, __builtin_amdgcn_rcpf(d0 * d1), acc[i][j]);
                }
            }
        }
    }

    // combine h-splits: hs 1..3 deposit partials, hs 0 reduces + softmax + write
    if (hs) {
#pragma unroll
        for (int i = 0; i < 4; ++i) {
            float4 v = make_float4(acc[i][0], acc[i][1], acc[i][2], acc[i][3]);
            *(float4*)&part[hs - 1][lane][i * 4] = v;
        }
    }
    __syncthreads();
    if (hs == 0) {
#pragma unroll
        for (int p = 0; p < 3; ++p)
#pragma unroll
            for (int i = 0; i < 4; ++i) {
                float4 v = *(const float4*)&part[p][lane][i * 4];
                acc[i][0] += v.x; acc[i][1] += v.y; acc[i][2] += v.z; acc[i][3] += v.w;
            }
        float e[4][4], t[4], ri[4];
#pragma unroll
        for (int i = 0; i < 4; ++i) {
            t[i] = 0.0f;
#pragma unroll
            for (int j = 0; j < 4; ++j) {
                e[i][j] = __builtin_amdgcn_exp2f((wsum - 2.0f * acc[i][j]) * LOG2E);
                t[i] += e[i][j];
            }
        }
#pragma unroll
        for (int o = 32; o; o >>= 1)
#pragma unroll
            for (int i = 0; i < 4; ++i) t[i] += __shfl_xor(t[i], o);
#pragma unroll
        for (int i = 0; i < 4; ++i) ri[i] = __builtin_amdgcn_rcpf(t[i]);
#pragma unroll
        for (int j = 0; j < 4; ++j) {
            float a0 = e[0][j] * ri[0], a1 = e[1][j] * ri[1];
            float a2 = e[2][j] * ri[2], a3 = e[3][j] * ri[3];
            size_t base = ((size_t)b * DIM + n0 + j) * DIM + M0;
            *(uint2*)&ANh[base] = make_uint2(hi2(a0, a1), hi2(a2, a3));
            *(uint2*)&ANl[base] = make_uint2(hi2(trunc_res(a0), trunc_res(a1)),
                                             hi2(trunc_res(a2), trunc_res(a3)));
        }
    }
}

// ---------------- av (MFMA): out[b][n][d] = sum_m attnN[n][m] * V[m][d] ----------------
__global__ __launch_bounds__(256) void av_mfma(
    const ushort_t* __restrict__ ANh, const ushort_t* __restrict__ ANl,
    const ushort_t* __restrict__ VTh, const ushort_t* __restrict__ VTl,
    float* __restrict__ out)
{
    __shared__ __align__(16) ushort_t Ah[64 * 64], Al[64 * 64], Bh[64 * 64], Bl[64 * 64];
    __shared__ __align__(16) float T[64][68];

    int b = blockIdx.y;
    int x = blockIdx.x;
    int R0 = (x >> 2) * 64, C0 = (x & 3) * 64;
    const ushort_t* Abh = ANh + (size_t)b * DIM * DIM;
    const ushort_t* Abl = ANl + (size_t)b * DIM * DIM;
    const ushort_t* Bbh = VTh + (size_t)b * DIM * DIM;
    const ushort_t* Bbl = VTl + (size_t)b * DIM * DIM;

    int tid = threadIdx.x;
    int w = tid >> 6, lane = tid & 63;
    int wr = w >> 1, wc = w & 1;
    int l15 = lane & 15, l4 = lane >> 4;
    int sr = tid >> 2, skq = (tid & 3) * 16;

    f32x4 acc[2][2] = {};
    uint4 ah0, ah1, al0, al1, bh0, bh1, bl0, bl1;
    {
        size_t aa = (size_t)(R0 + sr) * DIM + skq;
        size_t bb = (size_t)(C0 + sr) * DIM + skq;
        ah0 = *(const uint4*)&Abh[aa]; ah1 = *(const uint4*)&Abh[aa + 8];
        al0 = *(const uint4*)&Abl[aa]; al1 = *(const uint4*)&Abl[aa + 8];
        bh0 = *(const uint4*)&Bbh[bb]; bh1 = *(const uint4*)&Bbh[bb + 8];
        bl0 = *(const uint4*)&Bbl[bb]; bl1 = *(const uint4*)&Bbl[bb + 8];
    }

    for (int ks = 0; ks < 4; ++ks) {
        {
            int i0 = (sr * 64 + skq)     ^ ((sr & 7) << 3);
            int i1 = (sr * 64 + skq + 8) ^ ((sr & 7) << 3);
            *(uint4*)&Ah[i0] = ah0; *(uint4*)&Ah[i1] = ah1;
            *(uint4*)&Al[i0] = al0; *(uint4*)&Al[i1] = al1;
            *(uint4*)&Bh[i0] = bh0; *(uint4*)&Bh[i1] = bh1;
            *(uint4*)&Bl[i0] = bl0; *(uint4*)&Bl[i1] = bl1;
        }
        __syncthreads();
        if (ks < 3) {
            int K0 = (ks + 1) * 64;
            size_t aa = (size_t)(R0 + sr) * DIM + K0 + skq;
            size_t bb = (size_t)(C0 + sr) * DIM + K0 + skq;
            ah0 = *(const uint4*)&Abh[aa]; ah1 = *(const uint4*)&Abh[aa + 8];
            al0 = *(const uint4*)&Abl[aa]; al1 = *(const uint4*)&Abl[aa + 8];
            bh0 = *(const uint4*)&Bbh[bb]; bh1 = *(const uint4*)&Bbh[bb + 8];
            bl0 = *(const uint4*)&Bbl[bb]; bl1 = *(const uint4*)&Bbl[bb + 8];
        }
#pragma unroll
        for (int kk = 0; kk < 2; ++kk) {
            int kb = kk * 32 + l4 * 8;
            short8 ah[2], al[2], bh[2], bl[2];
#pragma unroll
            for (int h = 0; h < 2; ++h) {
                int arow = wr * 32 + h * 16 + l15;
                int aidx = (arow * 64 + kb) ^ ((arow & 7) << 3);
                ah[h] = *(const short8*)&Ah[aidx];
                al[h] = *(const short8*)&Al[aidx];
                int bcol = wc * 32 + h * 16 + l15;
                int bidx = (bcol * 64 + kb) ^ ((bcol & 7) << 3);
                bh[h] = *(const short8*)&Bh[bidx];
                bl[h] = *(const short8*)&Bl[bidx];
            }
#pragma unroll
            for (int i = 0; i < 2; ++i)
#pragma unroll
                for (int j = 0; j < 2; ++j) {
                    acc[i][j] = __builtin_amdgcn_mfma_f32_16x16x32_bf16(ah[i], bh[j], acc[i][j], 0, 0, 0);
                    acc[i][j] = __builtin_amdgcn_mfma_f32_16x16x32_bf16(ah[i], bl[j], acc[i][j], 0, 0, 0);
                    acc[i][j] = __builtin_amdgcn_mfma_f32_16x16x32_bf16(al[i], bh[j], acc[i][j], 0, 0, 0);
                }
        }
        __syncthreads();
    }

#pragma unroll
    for (int i = 0; i < 2; ++i)
#pragma unroll
        for (int j = 0; j < 2; ++j) {
            int row = wr * 32 + i * 16 + l4 * 4;
            int col = wc * 32 + j * 16 + l15;
#pragma unroll
            for (int v = 0; v < 4; ++v) T[row + v][col] = acc[i][j][v];
        }
    __syncthreads();
    {
        int r = tid >> 2, q = tid & 3;
        float* dst = &out[((size_t)b * DIM + R0 + r) * DIM + C0 + q * 16];
#pragma unroll
        for (int i = 0; i < 4; ++i)
            *(float4*)&dst[i * 4] = *(const float4*)&T[r][q * 16 + i * 4];
    }
}

extern "C" void kernel_launch(void* const* d_in, const int* in_sizes, int n_in,
                              void* d_out, int out_size, void* d_ws, size_t ws_size,
                              hipStream_t stream)
{
    const float* query = (const float*)d_in[0];
    const float* key   = (const float*)d_in[1];
    const float* value = (const float*)d_in[2];
    const float* Wq    = (const float*)d_in[3];
    const float* Wk    = (const float*)d_in[4];
    const float* Wv    = (const float*)d_in[5];
    float* out = (float*)d_out;

    float* EQ = (float*)d_ws;                     // [8][h][n] fp32
    float* EK = EQ + N_B * DIM * DIM;             // [8][m][h] fp32
    ushort_t* us = (ushort_t*)(EK + N_B * DIM * DIM);
    ushort_t* WqT_hi = us; us += DIM * DIM;
    ushort_t* WqT_lo = us; us += DIM * DIM;
    ushort_t* WkT_hi = us; us += DIM * DIM;
    ushort_t* WkT_lo = us; us += DIM * DIM;
    ushort_t* VT_hi  = us; us += N_B * DIM * DIM;
    ushort_t* VT_lo  = us; us += N_B * DIM * DIM;
    ushort_t* ANh    = us; us += N_B * DIM * DIM;
    ushort_t* ANl    = us; us += N_B * DIM * DIM;

    prep_kernel<<<160, 256, 0, stream>>>(Wq, Wk, value,
                                         WqT_hi, WqT_lo, WkT_hi, WkT_lo, VT_hi, VT_lo);
    proj_mfma<<<dim3(16, 16), 256, 0, stream>>>(query, key,
                                                WqT_hi, WqT_lo, WkT_hi, WkT_lo, EQ, EK);
    scores_softmax_kernel<<<dim3(64, 8), 256, 0, stream>>>(EQ, EK, Wv, ANh, ANl);
    av_mfma<<<dim3(16, 8), 256, 0, stream>>>(ANh, ANl, VT_hi, VT_lo, out);
}

// Round 14
// 46.039 us; speedup vs baseline: 1.0439x; 1.0076x over previous
//
#include <hip/hip_runtime.h>

#define N_B 8
#define DIM 256

constexpr float C2    = 2.8853900817779268f;   // 2*log2(e)
constexpr float LOG2E = 1.4426950408889634f;

typedef __attribute__((ext_vector_type(8))) short short8;
typedef __attribute__((ext_vector_type(4))) float f32x4;
typedef unsigned short ushort_t;

__device__ __forceinline__ unsigned hi2(float a, float b) {
    return (__float_as_uint(a) >> 16) | (__float_as_uint(b) & 0xFFFF0000u);
}
__device__ __forceinline__ float trunc_res(float a) {
    return a - __uint_as_float(__float_as_uint(a) & 0xFFFF0000u);
}

// ---------------- prep: transpose + bf16 hi/lo split ----------------
__global__ __launch_bounds__(256) void prep_kernel(
    const float* __restrict__ Wq, const float* __restrict__ Wk,
    const float* __restrict__ V,
    ushort_t* __restrict__ WqT_hi, ushort_t* __restrict__ WqT_lo,
    ushort_t* __restrict__ WkT_hi, ushort_t* __restrict__ WkT_lo,
    ushort_t* __restrict__ VT_hi,  ushort_t* __restrict__ VT_lo)
{
    __shared__ __align__(16) float T[64][68];
    int id = blockIdx.x;
    const float* src; ushort_t *dhi, *dlo; int t;
    if (id < 16)      { src = Wq; dhi = WqT_hi; dlo = WqT_lo; t = id; }
    else if (id < 32) { src = Wk; dhi = WkT_hi; dlo = WkT_lo; t = id - 16; }
    else {
        int v = id - 32; int b = v >> 4; t = v & 15;
        src = V + b * DIM * DIM; dhi = VT_hi + b * DIM * DIM; dlo = VT_lo + b * DIM * DIM;
    }
    int R0 = (t >> 2) * 64, C0 = (t & 3) * 64;
    int tt = threadIdx.x;
    int r = tt >> 2, q = tt & 3;
#pragma unroll
    for (int i = 0; i < 4; ++i)
        *(float4*)&T[r][q * 16 + i * 4] = *(const float4*)&src[(size_t)(R0 + r) * DIM + C0 + q * 16 + i * 4];
    __syncthreads();
    float f[16];
#pragma unroll
    for (int j = 0; j < 16; ++j) f[j] = T[q * 16 + j][r];
    unsigned h[8], l[8];
#pragma unroll
    for (int j = 0; j < 8; ++j) {
        h[j] = hi2(f[2 * j], f[2 * j + 1]);
        l[j] = hi2(trunc_res(f[2 * j]), trunc_res(f[2 * j + 1]));
    }
    size_t base = (size_t)(C0 + r) * DIM + R0 + q * 16;
    *(uint4*)&dhi[base]     = make_uint4(h[0], h[1], h[2], h[3]);
    *(uint4*)&dhi[base + 8] = make_uint4(h[4], h[5], h[6], h[7]);
    *(uint4*)&dlo[base]     = make_uint4(l[0], l[1], l[2], l[3]);
    *(uint4*)&dlo[base + 8] = make_uint4(l[4], l[5], l[6], l[7]);
}

// ---------------- proj (MFMA): EQ[b][h][n]=exp2(C2*(A@W)) transposed, EK[b][m][h] ----------------
__global__ __launch_bounds__(256) void proj_mfma(
    const float* __restrict__ query, const float* __restrict__ key,
    const ushort_t* __restrict__ WqT_hi, const ushort_t* __restrict__ WqT_lo,
    const ushort_t* __restrict__ WkT_hi, const ushort_t* __restrict__ WkT_lo,
    float* __restrict__ EQ, float* __restrict__ EK)
{
    __shared__ __align__(16) ushort_t Ah[64 * 64], Al[64 * 64], Bh[64 * 64], Bl[64 * 64];
    __shared__ __align__(16) float T[64][68];

    int y = blockIdx.y;
    int b = y >> 1; bool isK = y & 1;
    const float* A = (isK ? key : query) + b * DIM * DIM;
    const ushort_t* BThi = isK ? WkT_hi : WqT_hi;
    const ushort_t* BTlo = isK ? WkT_lo : WqT_lo;

    int x = blockIdx.x;
    int R0 = (x >> 2) * 64, C0 = (x & 3) * 64;

    int tid = threadIdx.x;
    int w = tid >> 6, lane = tid & 63;
    int wr = w >> 1, wc = w & 1;
    int l15 = lane & 15, l4 = lane >> 4;
    int sr = tid >> 2, skq = (tid & 3) * 16;

    f32x4 acc[2][2] = {};
    float4 areg0, areg1, areg2, areg3;
    uint4 bh0, bh1, bl0, bl1;

    {
        const float* ap = &A[(size_t)(R0 + sr) * DIM + skq];
        areg0 = *(const float4*)&ap[0];  areg1 = *(const float4*)&ap[4];
        areg2 = *(const float4*)&ap[8];  areg3 = *(const float4*)&ap[12];
        size_t bb = (size_t)(C0 + sr) * DIM + skq;
        bh0 = *(const uint4*)&BThi[bb]; bh1 = *(const uint4*)&BThi[bb + 8];
        bl0 = *(const uint4*)&BTlo[bb]; bl1 = *(const uint4*)&BTlo[bb + 8];
    }

    for (int ks = 0; ks < 4; ++ks) {
        {
            int i0 = (sr * 64 + skq)     ^ ((sr & 7) << 3);
            int i1 = (sr * 64 + skq + 8) ^ ((sr & 7) << 3);
            uint4 hv0 = make_uint4(hi2(areg0.x, areg0.y), hi2(areg0.z, areg0.w),
                                   hi2(areg1.x, areg1.y), hi2(areg1.z, areg1.w));
            uint4 hv1 = make_uint4(hi2(areg2.x, areg2.y), hi2(areg2.z, areg2.w),
                                   hi2(areg3.x, areg3.y), hi2(areg3.z, areg3.w));
            uint4 lv0 = make_uint4(hi2(trunc_res(areg0.x), trunc_res(areg0.y)),
                                   hi2(trunc_res(areg0.z), trunc_res(areg0.w)),
                                   hi2(trunc_res(areg1.x), trunc_res(areg1.y)),
                                   hi2(trunc_res(areg1.z), trunc_res(areg1.w)));
            uint4 lv1 = make_uint4(hi2(trunc_res(areg2.x), trunc_res(areg2.y)),
                                   hi2(trunc_res(areg2.z), trunc_res(areg2.w)),
                                   hi2(trunc_res(areg3.x), trunc_res(areg3.y)),
                                   hi2(trunc_res(areg3.z), trunc_res(areg3.w)));
            *(uint4*)&Ah[i0] = hv0; *(uint4*)&Ah[i1] = hv1;
            *(uint4*)&Al[i0] = lv0; *(uint4*)&Al[i1] = lv1;
            *(uint4*)&Bh[i0] = bh0; *(uint4*)&Bh[i1] = bh1;
            *(uint4*)&Bl[i0] = bl0; *(uint4*)&Bl[i1] = bl1;
        }
        __syncthreads();
        if (ks < 3) {
            int K0 = (ks + 1) * 64;
            const float* ap = &A[(size_t)(R0 + sr) * DIM + K0 + skq];
            areg0 = *(const float4*)&ap[0];  areg1 = *(const float4*)&ap[4];
            areg2 = *(const float4*)&ap[8];  areg3 = *(const float4*)&ap[12];
            size_t bb = (size_t)(C0 + sr) * DIM + K0 + skq;
            bh0 = *(const uint4*)&BThi[bb]; bh1 = *(const uint4*)&BThi[bb + 8];
            bl0 = *(const uint4*)&BTlo[bb]; bl1 = *(const uint4*)&BTlo[bb + 8];
        }
#pragma unroll
        for (int kk = 0; kk < 2; ++kk) {
            int kb = kk * 32 + l4 * 8;
            short8 ah[2], al[2], bh[2], bl[2];
#pragma unroll
            for (int h = 0; h < 2; ++h) {
                int arow = wr * 32 + h * 16 + l15;
                int aidx = (arow * 64 + kb) ^ ((arow & 7) << 3);
                ah[h] = *(const short8*)&Ah[aidx];
                al[h] = *(const short8*)&Al[aidx];
                int bcol = wc * 32 + h * 16 + l15;
                int bidx = (bcol * 64 + kb) ^ ((bcol & 7) << 3);
                bh[h] = *(const short8*)&Bh[bidx];
                bl[h] = *(const short8*)&Bl[bidx];
            }
#pragma unroll
            for (int i = 0; i < 2; ++i)
#pragma unroll
                for (int j = 0; j < 2; ++j) {
                    acc[i][j] = __builtin_amdgcn_mfma_f32_16x16x32_bf16(ah[i], bh[j], acc[i][j], 0, 0, 0);
                    acc[i][j] = __builtin_amdgcn_mfma_f32_16x16x32_bf16(ah[i], bl[j], acc[i][j], 0, 0, 0);
                    acc[i][j] = __builtin_amdgcn_mfma_f32_16x16x32_bf16(al[i], bh[j], acc[i][j], 0, 0, 0);
                }
        }
        __syncthreads();
    }

#pragma unroll
    for (int i = 0; i < 2; ++i)
#pragma unroll
        for (int j = 0; j < 2; ++j) {
            float ev[4];
#pragma unroll
            for (int v = 0; v < 4; ++v) ev[v] = __builtin_amdgcn_exp2f(C2 * acc[i][j][v]);
            int row = wr * 32 + i * 16 + l4 * 4;
            int col = wc * 32 + j * 16 + l15;
            if (isK) {
#pragma unroll
                for (int v = 0; v < 4; ++v) T[row + v][col] = ev[v];
            } else {
                *(float4*)&T[col][row] = make_float4(ev[0], ev[1], ev[2], ev[3]);
            }
        }
    __syncthreads();
    {
        int r = tid >> 2, q = tid & 3;
        float* dst = isK ? &EK[(size_t)b * DIM * DIM + (size_t)(R0 + r) * DIM + C0 + q * 16]
                         : &EQ[(size_t)b * DIM * DIM + (size_t)(C0 + r) * DIM + R0 + q * 16];
#pragma unroll
        for (int i = 0; i < 4; ++i)
            *(float4*)&dst[i * 4] = *(const float4*)&T[r][q * 16 + i * 4];
    }
}

// ---------------- fused scores + softmax(axis=n) -> attnN hi/lo bf16 [n][m] ----------------
// 512 thr = 8 waves = (4 h-splits) x (2 m-pairs); grid (64,8) = 512 blocks = 2/CU
// -> 4 waves/SIMD (launch_bounds(512,4), VGPR<=128). Barrier-free main loop,
// Q from global (L2-resident), ek/wv via small LDS broadcasts.
__global__ __launch_bounds__(512, 4) void scores_softmax_kernel(
    const float* __restrict__ EQ, const float* __restrict__ EK,
    const float* __restrict__ Wv,
    ushort_t* __restrict__ ANh, ushort_t* __restrict__ ANl)
{
    int b  = blockIdx.y;
    int M0 = blockIdx.x * 4;
    const float* Qb = EQ + b * DIM * DIM;   // [h][n]
    const float* Kb = EK + b * DIM * DIM;   // [m][h]

    __shared__ __align__(16) float Eks[4][DIM];       // 4 KB
    __shared__ __align__(16) float Ws[DIM];           // 1 KB
    __shared__ __align__(16) float part[3][2][64][8]; // 12 KB

    int tid = threadIdx.x;
    int w = tid >> 6, lane = tid & 63;
    int hs = w & 3, mg = w >> 2;      // h-split 0..3, m-pair 0..1
    int n0 = lane * 4;

    {   // stage Eks (4 m-rows x 256 h)
        int row = tid >> 7, c2 = (tid & 127) * 2;
        *(float2*)&Eks[row][c2] = *(const float2*)&Kb[(M0 + row) * DIM + c2];
    }
    if (tid < 64) *(float4*)&Ws[tid * 4] = *(const float4*)&Wv[tid * 4];

    float wsum = Wv[lane] + Wv[lane + 64] + Wv[lane + 128] + Wv[lane + 192];
#pragma unroll
    for (int o = 32; o; o >>= 1) wsum += __shfl_xor(wsum, o);
    __syncthreads();

    float acc[2][4] = {};   // [m-row][n]
    const float* qbase = Qb + (hs * 4) * DIM + n0;

    for (int c = 0; c < 16; ++c) {
        float4 wv4 = *(const float4*)&Ws[c * 16 + hs * 4];
        float4 ea4 = *(const float4*)&Eks[mg * 2][c * 16 + hs * 4];
        float4 eb4 = *(const float4*)&Eks[mg * 2 + 1][c * 16 + hs * 4];
        const float* qc = qbase + c * 16 * DIM;
        float4 q0 = *(const float4*)&qc[0];
        float4 q1 = *(const float4*)&qc[DIM];
        float4 q2 = *(const float4*)&qc[2 * DIM];
        float4 q3 = *(const float4*)&qc[3 * DIM];
        float q0a[4] = {q0.x, q0.y, q0.z, q0.w};
        float q1a[4] = {q1.x, q1.y, q1.z, q1.w};
        float q2a[4] = {q2.x, q2.y, q2.z, q2.w};
        float q3a[4] = {q3.x, q3.y, q3.z, q3.w};
#pragma unroll
        for (int j = 0; j < 4; ++j) {
            // h-pair (0,1): rows 0,1
            {
                float d0 = fmaf(q0a[j], ea4.x, 1.0f);
                float d1 = fmaf(q1a[j], ea4.y, 1.0f);
                float num = fmaf(wv4.y, d0, wv4.x * d1);
                acc[0][j] = fmaf(num, __builtin_amdgcn_rcpf(d0 * d1), acc[0][j]);
                float e0 = fmaf(q0a[j], eb4.x, 1.0f);
                float e1 = fmaf(q1a[j], eb4.y, 1.0f);
                float num2 = fmaf(wv4.y, e0, wv4.x * e1);
                acc[1][j] = fmaf(num2, __builtin_amdgcn_rcpf(e0 * e1), acc[1][j]);
            }
            // h-pair (2,3): rows 0,1
            {
                float d0 = fmaf(q2a[j], ea4.z, 1.0f);
                float d1 = fmaf(q3a[j], ea4.w, 1.0f);
                float num = fmaf(wv4.w, d0, wv4.z * d1);
                acc[0][j] = fmaf(num, __builtin_amdgcn_rcpf(d0 * d1), acc[0][j]);
                float e0 = fmaf(q2a[j], eb4.z, 1.0f);
                float e1 = fmaf(q3a[j], eb4.w, 1.0f);
                float num2 = fmaf(wv4.w, e0, wv4.z * e1);
                acc[1][j] = fmaf(num2, __builtin_amdgcn_rcpf(e0 * e1), acc[1][j]);
            }
        }
    }

    // combine h-splits: hs 1..3 deposit, hs 0 reduces + softmax + write
    if (hs) {
#pragma unroll
        for (int r = 0; r < 2; ++r) {
            float4 v = make_float4(acc[r][0], acc[r][1], acc[r][2], acc[r][3]);
            *(float4*)&part[hs - 1][mg][lane][r * 4] = v;
        }
    }
    __syncthreads();
    if (hs == 0) {
#pragma unroll
        for (int p = 0; p < 3; ++p)
#pragma unroll
            for (int r = 0; r < 2; ++r) {
                float4 v = *(const float4*)&part[p][mg][lane][r * 4];
                acc[r][0] += v.x; acc[r][1] += v.y; acc[r][2] += v.z; acc[r][3] += v.w;
            }
        float e[2][4], t[2];
#pragma unroll
        for (int r = 0; r < 2; ++r) {
            t[r] = 0.0f;
#pragma unroll
            for (int j = 0; j < 4; ++j) {
                e[r][j] = __builtin_amdgcn_exp2f((wsum - 2.0f * acc[r][j]) * LOG2E);
                t[r] += e[r][j];
            }
        }
#pragma unroll
        for (int o = 32; o; o >>= 1) { t[0] += __shfl_xor(t[0], o); t[1] += __shfl_xor(t[1], o); }
        float r0 = __builtin_amdgcn_rcpf(t[0]);
        float r1 = __builtin_amdgcn_rcpf(t[1]);
        int mcol = M0 + mg * 2;
#pragma unroll
        for (int j = 0; j < 4; ++j) {
            float a0 = e[0][j] * r0, a1 = e[1][j] * r1;
            size_t base = ((size_t)b * DIM + n0 + j) * DIM + mcol;
            *(unsigned*)&ANh[base] = hi2(a0, a1);
            *(unsigned*)&ANl[base] = hi2(trunc_res(a0), trunc_res(a1));
        }
    }
}

// ---------------- av (MFMA): out[b][n][d] = sum_m attnN[n][m] * V[m][d] ----------------
__global__ __launch_bounds__(256) void av_mfma(
    const ushort_t* __restrict__ ANh, const ushort_t* __restrict__ ANl,
    const ushort_t* __restrict__ VTh, const ushort_t* __restrict__ VTl,
    float* __restrict__ out)
{
    __shared__ __align__(16) ushort_t Ah[64 * 64], Al[64 * 64], Bh[64 * 64], Bl[64 * 64];
    __shared__ __align__(16) float T[64][68];

    int b = blockIdx.y;
    int x = blockIdx.x;
    int R0 = (x >> 2) * 64, C0 = (x & 3) * 64;
    const ushort_t* Abh = ANh + (size_t)b * DIM * DIM;
    const ushort_t* Abl = ANl + (size_t)b * DIM * DIM;
    const ushort_t* Bbh = VTh + (size_t)b * DIM * DIM;
    const ushort_t* Bbl = VTl + (size_t)b * DIM * DIM;

    int tid = threadIdx.x;
    int w = tid >> 6, lane = tid & 63;
    int wr = w >> 1, wc = w & 1;
    int l15 = lane & 15, l4 = lane >> 4;
    int sr = tid >> 2, skq = (tid & 3) * 16;

    f32x4 acc[2][2] = {};
    uint4 ah0, ah1, al0, al1, bh0, bh1, bl0, bl1;
    {
        size_t aa = (size_t)(R0 + sr) * DIM + skq;
        size_t bb = (size_t)(C0 + sr) * DIM + skq;
        ah0 = *(const uint4*)&Abh[aa]; ah1 = *(const uint4*)&Abh[aa + 8];
        al0 = *(const uint4*)&Abl[aa]; al1 = *(const uint4*)&Abl[aa + 8];
        bh0 = *(const uint4*)&Bbh[bb]; bh1 = *(const uint4*)&Bbh[bb + 8];
        bl0 = *(const uint4*)&Bbl[bb]; bl1 = *(const uint4*)&Bbl[bb + 8];
    }

    for (int ks = 0; ks < 4; ++ks) {
        {
            int i0 = (sr * 64 + skq)     ^ ((sr & 7) << 3);
            int i1 = (sr * 64 + skq + 8) ^ ((sr & 7) << 3);
            *(uint4*)&Ah[i0] = ah0; *(uint4*)&Ah[i1] = ah1;
            *(uint4*)&Al[i0] = al0; *(uint4*)&Al[i1] = al1;
            *(uint4*)&Bh[i0] = bh0; *(uint4*)&Bh[i1] = bh1;
            *(uint4*)&Bl[i0] = bl0; *(uint4*)&Bl[i1] = bl1;
        }
        __syncthreads();
        if (ks < 3) {
            int K0 = (ks + 1) * 64;
            size_t aa = (size_t)(R0 + sr) * DIM + K0 + skq;
            size_t bb = (size_t)(C0 + sr) * DIM + K0 + skq;
            ah0 = *(const uint4*)&Abh[aa]; ah1 = *(const uint4*)&Abh[aa + 8];
            al0 = *(const uint4*)&Abl[aa]; al1 = *(const uint4*)&Abl[aa + 8];
            bh0 = *(const uint4*)&Bbh[bb]; bh1 = *(const uint4*)&Bbh[bb + 8];
            bl0 = *(const uint4*)&Bbl[bb]; bl1 = *(const uint4*)&Bbl[bb + 8];
        }
#pragma unroll
        for (int kk = 0; kk < 2; ++kk) {
            int kb = kk * 32 + l4 * 8;
            short8 ah[2], al[2], bh[2], bl[2];
#pragma unroll
            for (int h = 0; h < 2; ++h) {
                int arow = wr * 32 + h * 16 + l15;
                int aidx = (arow * 64 + kb) ^ ((arow & 7) << 3);
                ah[h] = *(const short8*)&Ah[aidx];
                al[h] = *(const short8*)&Al[aidx];
                int bcol = wc * 32 + h * 16 + l15;
                int bidx = (bcol * 64 + kb) ^ ((bcol & 7) << 3);
                bh[h] = *(const short8*)&Bh[bidx];
                bl[h] = *(const short8*)&Bl[bidx];
            }
#pragma unroll
            for (int i = 0; i < 2; ++i)
#pragma unroll
                for (int j = 0; j < 2; ++j) {
                    acc[i][j] = __builtin_amdgcn_mfma_f32_16x16x32_bf16(ah[i], bh[j], acc[i][j], 0, 0, 0);
                    acc[i][j] = __builtin_amdgcn_mfma_f32_16x16x32_bf16(ah[i], bl[j], acc[i][j], 0, 0, 0);
                    acc[i][j] = __builtin_amdgcn_mfma_f32_16x16x32_bf16(al[i], bh[j], acc[i][j], 0, 0, 0);
                }
        }
        __syncthreads();
    }

#pragma unroll
    for (int i = 0; i < 2; ++i)
#pragma unroll
        for (int j = 0; j < 2; ++j) {
            int row = wr * 32 + i * 16 + l4 * 4;
            int col = wc * 32 + j * 16 + l15;
#pragma unroll
            for (int v = 0; v < 4; ++v) T[row + v][col] = acc[i][j][v];
        }
    __syncthreads();
    {
        int r = tid >> 2, q = tid & 3;
        float* dst = &out[((size_t)b * DIM + R0 + r) * DIM + C0 + q * 16];
#pragma unroll
        for (int i = 0; i < 4; ++i)
            *(float4*)&dst[i * 4] = *(const float4*)&T[r][q * 16 + i * 4];
    }
}

extern "C" void kernel_launch(void* const* d_in, const int* in_sizes, int n_in,
                              void* d_out, int out_size, void* d_ws, size_t ws_size,
                              hipStream_t stream)
{
    const float* query = (const float*)d_in[0];
    const float* key   = (const float*)d_in[1];
    const float* value = (const float*)d_in[2];
    const float* Wq    = (const float*)d_in[3];
    const float* Wk    = (const float*)d_in[4];
    const float* Wv    = (const float*)d_in[5];
    float* out = (float*)d_out;

    float* EQ = (float*)d_ws;                     // [8][h][n] fp32
    float* EK = EQ + N_B * DIM * DIM;             // [8][m][h] fp32
    ushort_t* us = (ushort_t*)(EK + N_B * DIM * DIM);
    ushort_t* WqT_hi = us; us += DIM * DIM;
    ushort_t* WqT_lo = us; us += DIM * DIM;
    ushort_t* WkT_hi = us; us += DIM * DIM;
    ushort_t* WkT_lo = us; us += DIM * DIM;
    ushort_t* VT_hi  = us; us += N_B * DIM * DIM;
    ushort_t* VT_lo  = us; us += N_B * DIM * DIM;
    ushort_t* ANh    = us; us += N_B * DIM * DIM;
    ushort_t* ANl    = us; us += N_B * DIM * DIM;

    prep_kernel<<<160, 256, 0, stream>>>(Wq, Wk, value,
                                         WqT_hi, WqT_lo, WkT_hi, WkT_lo, VT_hi, VT_lo);
    proj_mfma<<<dim3(16, 16), 256, 0, stream>>>(query, key,
                                                WqT_hi, WqT_lo, WkT_hi, WkT_lo, EQ, EK);
    scores_softmax_kernel<<<dim3(64, 8), 512, 0, stream>>>(EQ, EK, Wv, ANh, ANl);
    av_mfma<<<dim3(16, 8), 256, 0, stream>>>(ANh, ANl, VT_hi, VT_lo, out);
}

// Round 15
// 45.023 us; speedup vs baseline: 1.0675x; 1.0226x over previous
//
#include <hip/hip_runtime.h>

#define N_B 8
#define DIM 256

constexpr float C2    = 2.8853900817779268f;   // 2*log2(e)
constexpr float LOG2E = 1.4426950408889634f;

typedef __attribute__((ext_vector_type(8))) short short8;
typedef __attribute__((ext_vector_type(4))) float f32x4;
typedef unsigned short ushort_t;

__device__ __forceinline__ unsigned hi2(float a, float b) {
    return (__float_as_uint(a) >> 16) | (__float_as_uint(b) & 0xFFFF0000u);
}
__device__ __forceinline__ float trunc_res(float a) {
    return a - __uint_as_float(__float_as_uint(a) & 0xFFFF0000u);
}

// ---------------- proj (MFMA, in-kernel W transpose): ----------------
// EQ[b][h][n] = exp2(C2*(A@W)) transposed on store; EK[b][m][h] row-major.
// B-tile staged from W[k][col] global -> LDS [col][k] bf16 hi/lo (bank-spread kp).
__global__ __launch_bounds__(256) void proj_mfma(
    const float* __restrict__ query, const float* __restrict__ key,
    const float* __restrict__ Wq, const float* __restrict__ Wk,
    float* __restrict__ EQ, float* __restrict__ EK)
{
    __shared__ __align__(16) ushort_t Ah[64 * 64], Al[64 * 64], Bh[64 * 64], Bl[64 * 64];
    __shared__ __align__(16) float T[64][68];

    int y = blockIdx.y;
    int b = y >> 1; bool isK = y & 1;
    const float* A    = (isK ? key : query) + b * DIM * DIM;
    const float* Wsrc = isK ? Wk : Wq;

    int x = blockIdx.x;
    int R0 = (x >> 2) * 64, C0 = (x & 3) * 64;

    int tid = threadIdx.x;
    int w = tid >> 6, lane = tid & 63;
    int wr = w >> 1, wc = w & 1;
    int l15 = lane & 15, l4 = lane >> 4;

    int sr = tid >> 2, skq = (tid & 3) * 16;     // A staging: row, k-quad
    int kp = tid & 31, cg = tid >> 5;            // B staging: k-pair, col-octet

    f32x4 acc[2][2] = {};
    float4 areg0, areg1, areg2, areg3;
    float4 w00, w01, w10, w11;

    {   // prologue: stage-0 loads
        const float* ap = &A[(size_t)(R0 + sr) * DIM + skq];
        areg0 = *(const float4*)&ap[0];  areg1 = *(const float4*)&ap[4];
        areg2 = *(const float4*)&ap[8];  areg3 = *(const float4*)&ap[12];
        const float* wp0 = &Wsrc[(size_t)(2 * kp)     * DIM + C0 + cg * 8];
        const float* wp1 = &Wsrc[(size_t)(2 * kp + 1) * DIM + C0 + cg * 8];
        w00 = *(const float4*)&wp0[0]; w01 = *(const float4*)&wp0[4];
        w10 = *(const float4*)&wp1[0]; w11 = *(const float4*)&wp1[4];
    }

    for (int ks = 0; ks < 4; ++ks) {
        {   // A -> LDS (row-major k, XOR swizzle), converted hi/lo
            int i0 = (sr * 64 + skq)     ^ ((sr & 7) << 3);
            int i1 = (sr * 64 + skq + 8) ^ ((sr & 7) << 3);
            uint4 hv0 = make_uint4(hi2(areg0.x, areg0.y), hi2(areg0.z, areg0.w),
                                   hi2(areg1.x, areg1.y), hi2(areg1.z, areg1.w));
            uint4 hv1 = make_uint4(hi2(areg2.x, areg2.y), hi2(areg2.z, areg2.w),
                                   hi2(areg3.x, areg3.y), hi2(areg3.z, areg3.w));
            uint4 lv0 = make_uint4(hi2(trunc_res(areg0.x), trunc_res(areg0.y)),
                                   hi2(trunc_res(areg0.z), trunc_res(areg0.w)),
                                   hi2(trunc_res(areg1.x), trunc_res(areg1.y)),
                                   hi2(trunc_res(areg1.z), trunc_res(areg1.w)));
            uint4 lv1 = make_uint4(hi2(trunc_res(areg2.x), trunc_res(areg2.y)),
                                   hi2(trunc_res(areg2.z), trunc_res(areg2.w)),
                                   hi2(trunc_res(areg3.x), trunc_res(areg3.y)),
                                   hi2(trunc_res(areg3.z), trunc_res(areg3.w)));
            *(uint4*)&Ah[i0] = hv0; *(uint4*)&Ah[i1] = hv1;
            *(uint4*)&Al[i0] = lv0; *(uint4*)&Al[i1] = lv1;
            // B (W^T) -> LDS [col][k] hi/lo: 8 cols x 1 dword (k-pair) each
            float a0[8] = {w00.x, w00.y, w00.z, w00.w, w01.x, w01.y, w01.z, w01.w};
            float a1[8] = {w10.x, w10.y, w10.z, w10.w, w11.x, w11.y, w11.z, w11.w};
#pragma unroll
            for (int c = 0; c < 8; ++c) {
                int col = cg * 8 + c;
                int idx = (col * 64 + 2 * kp) ^ ((col & 7) << 3);
                *(unsigned*)&Bh[idx] = hi2(a0[c], a1[c]);
                *(unsigned*)&Bl[idx] = hi2(trunc_res(a0[c]), trunc_res(a1[c]));
            }
        }
        __syncthreads();
        if (ks < 3) {   // issue next-stage loads early
            int K0 = (ks + 1) * 64;
            const float* ap = &A[(size_t)(R0 + sr) * DIM + K0 + skq];
            areg0 = *(const float4*)&ap[0];  areg1 = *(const float4*)&ap[4];
            areg2 = *(const float4*)&ap[8];  areg3 = *(const float4*)&ap[12];
            const float* wp0 = &Wsrc[(size_t)(K0 + 2 * kp)     * DIM + C0 + cg * 8];
            const float* wp1 = &Wsrc[(size_t)(K0 + 2 * kp + 1) * DIM + C0 + cg * 8];
            w00 = *(const float4*)&wp0[0]; w01 = *(const float4*)&wp0[4];
            w10 = *(const float4*)&wp1[0]; w11 = *(const float4*)&wp1[4];
        }
#pragma unroll
        for (int kk = 0; kk < 2; ++kk) {
            int kb = kk * 32 + l4 * 8;
            short8 ah[2], al[2], bh[2], bl[2];
#pragma unroll
            for (int h = 0; h < 2; ++h) {
                int arow = wr * 32 + h * 16 + l15;
                int aidx = (arow * 64 + kb) ^ ((arow & 7) << 3);
                ah[h] = *(const short8*)&Ah[aidx];
                al[h] = *(const short8*)&Al[aidx];
                int bcol = wc * 32 + h * 16 + l15;
                int bidx = (bcol * 64 + kb) ^ ((bcol & 7) << 3);
                bh[h] = *(const short8*)&Bh[bidx];
                bl[h] = *(const short8*)&Bl[bidx];
            }
#pragma unroll
            for (int i = 0; i < 2; ++i)
#pragma unroll
                for (int j = 0; j < 2; ++j) {
                    acc[i][j] = __builtin_amdgcn_mfma_f32_16x16x32_bf16(ah[i], bh[j], acc[i][j], 0, 0, 0);
                    acc[i][j] = __builtin_amdgcn_mfma_f32_16x16x32_bf16(ah[i], bl[j], acc[i][j], 0, 0, 0);
                    acc[i][j] = __builtin_amdgcn_mfma_f32_16x16x32_bf16(al[i], bh[j], acc[i][j], 0, 0, 0);
                }
        }
        __syncthreads();
    }

    // epilogue: exp2(C2*x), bounce-transpose, coalesced global writes
#pragma unroll
    for (int i = 0; i < 2; ++i)
#pragma unroll
        for (int j = 0; j < 2; ++j) {
            float ev[4];
#pragma unroll
            for (int v = 0; v < 4; ++v) ev[v] = __builtin_amdgcn_exp2f(C2 * acc[i][j][v]);
            int row = wr * 32 + i * 16 + l4 * 4;
            int col = wc * 32 + j * 16 + l15;
            if (isK) {
#pragma unroll
                for (int v = 0; v < 4; ++v) T[row + v][col] = ev[v];
            } else {
                *(float4*)&T[col][row] = make_float4(ev[0], ev[1], ev[2], ev[3]);
            }
        }
    __syncthreads();
    {
        int r = tid >> 2, q = tid & 3;
        float* dst = isK ? &EK[(size_t)b * DIM * DIM + (size_t)(R0 + r) * DIM + C0 + q * 16]
                         : &EQ[(size_t)b * DIM * DIM + (size_t)(C0 + r) * DIM + R0 + q * 16];
#pragma unroll
        for (int i = 0; i < 4; ++i)
            *(float4*)&dst[i * 4] = *(const float4*)&T[r][q * 16 + i * 4];
    }
}

// ---------------- fused scores + softmax(axis=n) -> attnN hi/lo bf16 [n][m] ----------------
// (R11 structure, proven): barrier-free main loop, Q from global (L2), ek/wv LDS broadcast.
__global__ __launch_bounds__(256, 2) void scores_softmax_kernel(
    const float* __restrict__ EQ, const float* __restrict__ EK,
    const float* __restrict__ Wv,
    ushort_t* __restrict__ ANh, ushort_t* __restrict__ ANl)
{
    int b  = blockIdx.y;
    int M0 = blockIdx.x * 4;
    const float* Qb = EQ + b * DIM * DIM;   // [h][n]
    const float* Kb = EK + b * DIM * DIM;   // [m][h]

    __shared__ __align__(16) float Eks[4][DIM];     // 4 KB
    __shared__ __align__(16) float Ws[DIM];         // 1 KB
    __shared__ __align__(16) float part[3][64][16]; // 12 KB

    int tid  = threadIdx.x;
    int hs = tid >> 6, lane = tid & 63;   // wave = h-split 0..3
    int n0 = lane * 4;

    {
        int row = tid >> 6, h4 = (tid & 63) * 4;
        *(float4*)&Eks[row][h4] = *(const float4*)&Kb[(M0 + row) * DIM + h4];
    }
    if (tid < 64) *(float4*)&Ws[tid * 4] = *(const float4*)&Wv[tid * 4];

    float wsum = Wv[lane] + Wv[lane + 64] + Wv[lane + 128] + Wv[lane + 192];
#pragma unroll
    for (int o = 32; o; o >>= 1) wsum += __shfl_xor(wsum, o);
    __syncthreads();

    float acc[4][4] = {};
    const float* qbase = Qb + (hs * 4) * 256 + n0;

#pragma unroll 2
    for (int c = 0; c < 16; ++c) {
        float4 wv4 = *(const float4*)&Ws[c * 16 + hs * 4];
        float wva[4] = {wv4.x, wv4.y, wv4.z, wv4.w};
        float eka[4][4];
#pragma unroll
        for (int i = 0; i < 4; ++i) {
            float4 e4 = *(const float4*)&Eks[i][c * 16 + hs * 4];
            eka[i][0] = e4.x; eka[i][1] = e4.y; eka[i][2] = e4.z; eka[i][3] = e4.w;
        }
        const float* qc = qbase + c * 16 * 256;
#pragma unroll
        for (int hh = 0; hh < 2; ++hh) {
            float4 q0 = *(const float4*)&qc[(hh * 2) * 256];
            float4 q1 = *(const float4*)&qc[(hh * 2 + 1) * 256];
            float q0a[4] = {q0.x, q0.y, q0.z, q0.w};
            float q1a[4] = {q1.x, q1.y, q1.z, q1.w};
            float w0 = wva[hh * 2], w1 = wva[hh * 2 + 1];
#pragma unroll
            for (int i = 0; i < 4; ++i) {
                float e0 = eka[i][hh * 2], e1 = eka[i][hh * 2 + 1];
#pragma unroll
                for (int j = 0; j < 4; ++j) {
                    float d0 = fmaf(q0a[j], e0, 1.0f);
                    float d1 = fmaf(q1a[j], e1, 1.0f);
                    float num = fmaf(w0, d1, w1 * d0);
                    acc[i][j] = fmaf(num, __builtin_amdgcn_rcpf(d0 * d1), acc[i][j]);
                }
            }
        }
    }

    if (hs) {
#pragma unroll
        for (int i = 0; i < 4; ++i) {
            float4 v = make_float4(acc[i][0], acc[i][1], acc[i][2], acc[i][3]);
            *(float4*)&part[hs - 1][lane][i * 4] = v;
        }
    }
    __syncthreads();
    if (hs == 0) {
#pragma unroll
        for (int p = 0; p < 3; ++p)
#pragma unroll
            for (int i = 0; i < 4; ++i) {
                float4 v = *(const float4*)&part[p][lane][i * 4];
                acc[i][0] += v.x; acc[i][1] += v.y; acc[i][2] += v.z; acc[i][3] += v.w;
            }
        float e[4][4], t[4], ri[4];
#pragma unroll
        for (int i = 0; i < 4; ++i) {
            t[i] = 0.0f;
#pragma unroll
            for (int j = 0; j < 4; ++j) {
                e[i][j] = __builtin_amdgcn_exp2f((wsum - 2.0f * acc[i][j]) * LOG2E);
                t[i] += e[i][j];
            }
        }
#pragma unroll
        for (int o = 32; o; o >>= 1)
#pragma unroll
            for (int i = 0; i < 4; ++i) t[i] += __shfl_xor(t[i], o);
#pragma unroll
        for (int i = 0; i < 4; ++i) ri[i] = __builtin_amdgcn_rcpf(t[i]);
#pragma unroll
        for (int j = 0; j < 4; ++j) {
            float a0 = e[0][j] * ri[0], a1 = e[1][j] * ri[1];
            float a2 = e[2][j] * ri[2], a3 = e[3][j] * ri[3];
            size_t base = ((size_t)b * DIM + n0 + j) * DIM + M0;
            *(uint2*)&ANh[base] = make_uint2(hi2(a0, a1), hi2(a2, a3));
            *(uint2*)&ANl[base] = make_uint2(hi2(trunc_res(a0), trunc_res(a1)),
                                             hi2(trunc_res(a2), trunc_res(a3)));
        }
    }
}

// ---------------- av (MFMA, in-kernel V transpose): out[n][d] = sum_m attn[n][m] V[m][d] ----
__global__ __launch_bounds__(256) void av_mfma(
    const ushort_t* __restrict__ ANh, const ushort_t* __restrict__ ANl,
    const float* __restrict__ value, float* __restrict__ out)
{
    __shared__ __align__(16) ushort_t Ah[64 * 64], Al[64 * 64], Bh[64 * 64], Bl[64 * 64];
    __shared__ __align__(16) float T[64][68];

    int b = blockIdx.y;
    int x = blockIdx.x;
    int R0 = (x >> 2) * 64, C0 = (x & 3) * 64;   // n-tile, d-tile
    const ushort_t* Abh = ANh + (size_t)b * DIM * DIM;
    const ushort_t* Abl = ANl + (size_t)b * DIM * DIM;
    const float*    Vb  = value + (size_t)b * DIM * DIM;   // [m][d]

    int tid = threadIdx.x;
    int w = tid >> 6, lane = tid & 63;
    int wr = w >> 1, wc = w & 1;
    int l15 = lane & 15, l4 = lane >> 4;
    int sr = tid >> 2, skq = (tid & 3) * 16;
    int kp = tid & 31, cg = tid >> 5;            // V staging: m-pair, d-octet

    f32x4 acc[2][2] = {};
    uint4 ah0, ah1, al0, al1;
    float4 v00, v01, v10, v11;
    {
        size_t aa = (size_t)(R0 + sr) * DIM + skq;
        ah0 = *(const uint4*)&Abh[aa]; ah1 = *(const uint4*)&Abh[aa + 8];
        al0 = *(const uint4*)&Abl[aa]; al1 = *(const uint4*)&Abl[aa + 8];
        const float* vp0 = &Vb[(size_t)(2 * kp)     * DIM + C0 + cg * 8];
        const float* vp1 = &Vb[(size_t)(2 * kp + 1) * DIM + C0 + cg * 8];
        v00 = *(const float4*)&vp0[0]; v01 = *(const float4*)&vp0[4];
        v10 = *(const float4*)&vp1[0]; v11 = *(const float4*)&vp1[4];
    }

    for (int ks = 0; ks < 4; ++ks) {
        {
            int i0 = (sr * 64 + skq)     ^ ((sr & 7) << 3);
            int i1 = (sr * 64 + skq + 8) ^ ((sr & 7) << 3);
            *(uint4*)&Ah[i0] = ah0; *(uint4*)&Ah[i1] = ah1;
            *(uint4*)&Al[i0] = al0; *(uint4*)&Al[i1] = al1;
            float a0[8] = {v00.x, v00.y, v00.z, v00.w, v01.x, v01.y, v01.z, v01.w};
            float a1[8] = {v10.x, v10.y, v10.z, v10.w, v11.x, v11.y, v11.z, v11.w};
#pragma unroll
            for (int c = 0; c < 8; ++c) {
                int col = cg * 8 + c;
                int idx = (col * 64 + 2 * kp) ^ ((col & 7) << 3);
                *(unsigned*)&Bh[idx] = hi2(a0[c], a1[c]);
                *(unsigned*)&Bl[idx] = hi2(trunc_res(a0[c]), trunc_res(a1[c]));
            }
        }
        __syncthreads();
        if (ks < 3) {
            int K0 = (ks + 1) * 64;
            size_t aa = (size_t)(R0 + sr) * DIM + K0 + skq;
            ah0 = *(const uint4*)&Abh[aa]; ah1 = *(const uint4*)&Abh[aa + 8];
            al0 = *(const uint4*)&Abl[aa]; al1 = *(const uint4*)&Abl[aa + 8];
            const float* vp0 = &Vb[(size_t)(K0 + 2 * kp)     * DIM + C0 + cg * 8];
            const float* vp1 = &Vb[(size_t)(K0 + 2 * kp + 1) * DIM + C0 + cg * 8];
            v00 = *(const float4*)&vp0[0]; v01 = *(const float4*)&vp0[4];
            v10 = *(const float4*)&vp1[0]; v11 = *(const float4*)&vp1[4];
        }
#pragma unroll
        for (int kk = 0; kk < 2; ++kk) {
            int kb = kk * 32 + l4 * 8;
            short8 ah[2], al[2], bh[2], bl[2];
#pragma unroll
            for (int h = 0; h < 2; ++h) {
                int arow = wr * 32 + h * 16 + l15;
                int aidx = (arow * 64 + kb) ^ ((arow & 7) << 3);
                ah[h] = *(const short8*)&Ah[aidx];
                al[h] = *(const short8*)&Al[aidx];
                int bcol = wc * 32 + h * 16 + l15;
                int bidx = (bcol * 64 + kb) ^ ((bcol & 7) << 3);
                bh[h] = *(const short8*)&Bh[bidx];
                bl[h] = *(const short8*)&Bl[bidx];
            }
#pragma unroll
            for (int i = 0; i < 2; ++i)
#pragma unroll
                for (int j = 0; j < 2; ++j) {
                    acc[i][j] = __builtin_amdgcn_mfma_f32_16x16x32_bf16(ah[i], bh[j], acc[i][j], 0, 0, 0);
                    acc[i][j] = __builtin_amdgcn_mfma_f32_16x16x32_bf16(ah[i], bl[j], acc[i][j], 0, 0, 0);
                    acc[i][j] = __builtin_amdgcn_mfma_f32_16x16x32_bf16(al[i], bh[j], acc[i][j], 0, 0, 0);
                }
        }
        __syncthreads();
    }

#pragma unroll
    for (int i = 0; i < 2; ++i)
#pragma unroll
        for (int j = 0; j < 2; ++j) {
            int row = wr * 32 + i * 16 + l4 * 4;
            int col = wc * 32 + j * 16 + l15;
#pragma unroll
            for (int v = 0; v < 4; ++v) T[row + v][col] = acc[i][j][v];
        }
    __syncthreads();
    {
        int r = tid >> 2, q = tid & 3;
        float* dst = &out[((size_t)b * DIM + R0 + r) * DIM + C0 + q * 16];
#pragma unroll
        for (int i = 0; i < 4; ++i)
            *(float4*)&dst[i * 4] = *(const float4*)&T[r][q * 16 + i * 4];
    }
}

extern "C" void kernel_launch(void* const* d_in, const int* in_sizes, int n_in,
                              void* d_out, int out_size, void* d_ws, size_t ws_size,
                              hipStream_t stream)
{
    const float* query = (const float*)d_in[0];
    const float* key   = (const float*)d_in[1];
    const float* value = (const float*)d_in[2];
    const float* Wq    = (const float*)d_in[3];
    const float* Wk    = (const float*)d_in[4];
    const float* Wv    = (const float*)d_in[5];
    float* out = (float*)d_out;

    float* EQ = (float*)d_ws;                     // [8][h][n] fp32
    float* EK = EQ + N_B * DIM * DIM;             // [8][m][h] fp32
    ushort_t* us = (ushort_t*)(EK + N_B * DIM * DIM);
    ushort_t* ANh = us; us += N_B * DIM * DIM;
    ushort_t* ANl = us; us += N_B * DIM * DIM;

    proj_mfma            <<<dim3(16, 16), 256, 0, stream>>>(query, key, Wq, Wk, EQ, EK);
    scores_softmax_kernel<<<dim3(64, 8),  256, 0, stream>>>(EQ, EK, Wv, ANh, ANl);
    av_mfma              <<<dim3(16, 8),  256, 0, stream>>>(ANh, ANl, value, out);
}